// Round 4
// baseline (515.682 us; speedup 1.0000x reference)
//
#include <hip/hip_runtime.h>

// NAM inference via sorted-prefix decomposition (full fp32, no MFMA).
// h_u = clip(d*e_u,0,1), d = x[b,f]-exu_b[f], e_u = exp(exu_w[f,u]) > 0.
//   d <= 0        -> h = 0      -> h2 = relu(b1)           (per-f table)
//   d*emin >= 1   -> h = 1 all  -> h2 = relu(colsum + b1)  (per-f table, exact)
//   middle        -> h_u = min(d*e_u, 1). With u sorted by e_u ascending and
//                    r = #{e_u < 1/d}:  hT W1 = d*S_r - T_r + colsum, where
//                    S_r,T_r are prefix sums of (e_u*W1row, W1row) in sorted order.
// One pass over W1 (268 MB, the structural floor) computes colsum AND snapshots
// every middle row at its rank. B=2048, F=128, U=1024, V=512, C=10.

#define F_ 128
#define U_ 1024
#define V_ 512
#define C_ 10
#define B_ 2048
#define UN 16

// ---------------- K1: per-f bitonic sort of (e_bits,u); emin; biasc; zeros ----------------
__global__ void nam_sort(const float* __restrict__ exu_w, const float* __restrict__ b2,
                         const float* __restrict__ b_out,
                         unsigned long long* __restrict__ skeys_g,
                         float* __restrict__ emin, float* __restrict__ biasc,
                         int* __restrict__ count, float* __restrict__ logits_mid)
{
  const int bid = blockIdx.x, t = threadIdx.x;
  if (bid < F_) {
    __shared__ unsigned long long keys[1024];
    for (int i = t; i < U_; i += 256) {
      float e = expf(exu_w[(size_t)bid * U_ + i]);
      keys[i] = ((unsigned long long)__builtin_bit_cast(unsigned, e) << 32) | (unsigned)i;
    }
    __syncthreads();
    for (int k = 2; k <= 1024; k <<= 1)
      for (int j = k >> 1; j > 0; j >>= 1) {
        for (int i = t; i < 1024; i += 256) {
          const int p = i ^ j;
          if (p > i) {
            unsigned long long a = keys[i], b = keys[p];
            const bool up = ((i & k) == 0);
            if (up ? (a > b) : (a < b)) { keys[i] = b; keys[p] = a; }
          }
        }
        __syncthreads();
      }
    for (int i = t; i < 1024; i += 256) skeys_g[(size_t)bid * U_ + i] = keys[i];
    if (t == 0) emin[bid] = __builtin_bit_cast(float, (unsigned)(keys[0] >> 32));
  } else if (bid == F_) {
    if (t < C_) {
      float s = b_out[t];
      for (int ff = 0; ff < F_; ++ff) s += b2[ff * C_ + t];
      biasc[t] = s;
    } else if (t >= 32 && t < 32 + F_) {
      count[t - 32] = 0;
    }
  } else {
    const int idx = (bid - F_ - 1) * 256 + t;   // 80 blocks -> 20480 = B_*C_
    logits_mid[idx] = 0.f;
  }
}

// ---------------- K2: classify rows, build per-feature middle lists ----------------
__global__ void nam_classify(const float* __restrict__ x, const float* __restrict__ exu_b,
                             const float* __restrict__ emin,
                             int* __restrict__ count, int* __restrict__ listb)
{
  const int t = threadIdx.x;
  const int f = t & 127, sub = t >> 7;
  const int b = blockIdx.x * 2 + sub;
  const float d = x[(size_t)b * F_ + f] - exu_b[f];
  if (d > 0.f && d * emin[f] < 1.f) {
    const int idx = atomicAdd(count + f, 1);
    listb[f * B_ + idx] = b;
  }
}

// ---------------- K3: sorted stream over W1: colsum + middle-row snapshots ----------------
// Grid: 256 = f(128) x half(2). Block: 128 thr; each thread owns 2 v columns (dwordx2).
__global__ __launch_bounds__(128) void nam_stream(
    const float* __restrict__ x, const float* __restrict__ exu_b,
    const float* __restrict__ W1,
    const unsigned long long* __restrict__ skeys_g,
    const int* __restrict__ listb, const int* __restrict__ count,
    float* __restrict__ colsum1, float* __restrict__ h2pre,
    int* __restrict__ bout)
{
  __shared__ unsigned long long skeys[1024];  // sorted (e_bits, u)
  __shared__ unsigned pkey[2048];             // (r<<11 | list_idx), sorted
  __shared__ float    darr[2048];
  __shared__ int      barr[2048];

  const int bx   = blockIdx.x;
  const int f    = bx >> 1;
  const int half = bx & 1;
  const int tid  = threadIdx.x;

  for (int i = tid; i < 1024; i += 128) skeys[i] = skeys_g[(size_t)f * U_ + i];
  const int nmid = count[f];
  const float bfv = exu_b[f];
  __syncthreads();

  // build (rank, idx) keys via binary search on sorted e
  for (int i = tid; i < nmid; i += 128) {
    const int b = listb[f * B_ + i];
    const float d = x[(size_t)b * F_ + f] - bfv;
    darr[i] = d;
    barr[i] = b;
    const float thr = 1.0f / d;
    int lo = 0, hi = 1024;
#pragma unroll
    for (int s = 0; s < 10; ++s) {
      const int mid = (lo + hi) >> 1;
      const float e = __builtin_bit_cast(float, (unsigned)(skeys[mid] >> 32));
      if (e < thr) lo = mid + 1; else hi = mid;
      if (lo >= hi) { /* converged; keep uniform trip count */ }
    }
    pkey[i] = ((unsigned)lo << 11) | (unsigned)i;
  }
  int npow2 = 2;
  while (npow2 < nmid) npow2 <<= 1;
  for (int i = tid; i < npow2; i += 128)
    if (i >= nmid) pkey[i] = 0xFFFFFFFFu;
  __syncthreads();
  if (nmid > 1) {
    for (int k = 2; k <= npow2; k <<= 1)
      for (int j = k >> 1; j > 0; j >>= 1) {
        for (int i = tid; i < npow2; i += 128) {
          const int p = i ^ j;
          if (p > i) {
            unsigned a = pkey[i], b = pkey[p];
            const bool up = ((i & k) == 0);
            if (up ? (a > b) : (a < b)) { pkey[i] = b; pkey[p] = a; }
          }
        }
        __syncthreads();
      }
  }

  // ---- streamed prefix pass ----
  const float* Wf = W1 + (size_t)f * (U_ * V_) + half * 256 + 2 * tid;
  typedef __attribute__((ext_vector_type(2))) float f2;
  f2 cur[UN], nxt[UN];
  float ecur[UN], enxt[UN];
#pragma unroll
  for (int q = 0; q < UN; ++q) {
    const unsigned long long kk = skeys[q];
    cur[q] = *(const f2*)(Wf + ((unsigned)(kk & 1023u) << 9));
    ecur[q] = __builtin_bit_cast(float, (unsigned)(kk >> 32));
  }
  float S0 = 0.f, S1 = 0.f, T0 = 0.f, T1 = 0.f;
  int pp = 0;
  int next_r = (nmid > 0) ? (int)(pkey[0] >> 11) : 99999;

  for (int blk = 0; blk < 1024 / UN; ++blk) {
    if (blk < 1024 / UN - 1) {
#pragma unroll
      for (int q = 0; q < UN; ++q) {
        const unsigned long long kk = skeys[(blk + 1) * UN + q];
        nxt[q] = *(const f2*)(Wf + ((unsigned)(kk & 1023u) << 9));
        enxt[q] = __builtin_bit_cast(float, (unsigned)(kk >> 32));
      }
    }
#pragma unroll
    for (int q = 0; q < UN; ++q) {
      const int i = blk * UN + q;
      while (pp < nmid && next_r <= i) {   // snapshot BEFORE processing rank i
        const unsigned pk = pkey[pp];
        const int idx = (int)(pk & 2047u);
        const float dd = darr[idx];
        f2 outv;
        outv.x = dd * S0 - T0;
        outv.y = dd * S1 - T1;
        *(f2*)(h2pre + ((size_t)f * B_ + pp) * V_ + half * 256 + 2 * tid) = outv;
        if (tid == 0 && half == 0) bout[f * B_ + pp] = barr[idx];
        ++pp;
        next_r = (pp < nmid) ? (int)(pkey[pp] >> 11) : 99999;
      }
      const float e = ecur[q];
      const f2 wv = cur[q];
      S0 = fmaf(e, wv.x, S0);
      S1 = fmaf(e, wv.y, S1);
      T0 += wv.x;
      T1 += wv.y;
    }
#pragma unroll
    for (int q = 0; q < UN; ++q) { cur[q] = nxt[q]; ecur[q] = enxt[q]; }
  }
  // pops with r == 1024 (all-active rows)
  while (pp < nmid) {
    const unsigned pk = pkey[pp];
    const int idx = (int)(pk & 2047u);
    const float dd = darr[idx];
    f2 outv;
    outv.x = dd * S0 - T0;
    outv.y = dd * S1 - T1;
    *(f2*)(h2pre + ((size_t)f * B_ + pp) * V_ + half * 256 + 2 * tid) = outv;
    if (tid == 0 && half == 0) bout[f * B_ + pp] = barr[idx];
    ++pp;
  }
  // exact fp32 colsum of this v-slice
  f2 cs; cs.x = T0; cs.y = T1;
  *(f2*)(colsum1 + f * V_ + half * 256 + 2 * tid) = cs;
}

// ---------------- K4: finalize middles: h2 = relu(pre+colsum+b1); logits += h2 @ W2 ----------------
__global__ void nam_fin_mid(const int* __restrict__ count, const int* __restrict__ bout,
                            const float* __restrict__ h2pre, const float* __restrict__ colsum1,
                            const float* __restrict__ b1, const float* __restrict__ W2,
                            float* __restrict__ logits_mid)
{
  const int f = blockIdx.x, t = threadIdx.x;
  const int wave = t >> 6, lane = t & 63;
  const int nmid = count[f];
  for (int row = wave; row < nmid; row += 4) {
    const int b = bout[f * B_ + row];
    const float* pre = h2pre + ((size_t)f * B_ + row) * V_ + lane * 8;
    const float* csp = colsum1 + f * V_ + lane * 8;
    const float* b1p = b1 + (size_t)f * V_ + lane * 8;
    float acc[C_];
#pragma unroll
    for (int c = 0; c < C_; ++c) acc[c] = 0.f;
#pragma unroll
    for (int j = 0; j < 8; ++j) {
      const float h = fmaxf(pre[j] + csp[j] + b1p[j], 0.f);
      const float* w2p = W2 + ((size_t)f * V_ + lane * 8 + j) * C_;
#pragma unroll
      for (int c = 0; c < C_; ++c) acc[c] = fmaf(h, w2p[c], acc[c]);
    }
#pragma unroll
    for (int off = 32; off > 0; off >>= 1)
#pragma unroll
      for (int c = 0; c < C_; ++c) acc[c] += __shfl_down(acc[c], off);
    if (lane == 0)
#pragma unroll
      for (int c = 0; c < C_; ++c) atomicAdd(logits_mid + (size_t)b * C_ + c, acc[c]);
  }
}

// ---------------- K5: per-feature zero/one class tables ----------------
__global__ void nam_tables(const float* __restrict__ colsum1, const float* __restrict__ b1,
                           const float* __restrict__ W2,
                           float* __restrict__ zlog, float* __restrict__ olog)
{
  const int f = blockIdx.x, t = threadIdx.x;
  float a0[C_], a1[C_];
#pragma unroll
  for (int c = 0; c < C_; ++c) { a0[c] = 0.f; a1[c] = 0.f; }
#pragma unroll
  for (int rep = 0; rep < 2; ++rep) {
    const int v = t + rep * 256;
    const float b1v = b1[(size_t)f * V_ + v];
    const float hz = fmaxf(b1v, 0.f);
    const float ho = fmaxf(colsum1[(size_t)f * V_ + v] + b1v, 0.f);
    const float* w2p = W2 + ((size_t)f * V_ + v) * C_;
#pragma unroll
    for (int c = 0; c < C_; ++c) {
      const float wv = w2p[c];
      a0[c] += hz * wv;
      a1[c] += ho * wv;
    }
  }
#pragma unroll
  for (int off = 32; off > 0; off >>= 1)
#pragma unroll
    for (int c = 0; c < C_; ++c) {
      a0[c] += __shfl_down(a0[c], off);
      a1[c] += __shfl_down(a1[c], off);
    }
  __shared__ float red[4][2 * C_];
  const int wv_ = t >> 6, ln = t & 63;
  if (ln == 0)
#pragma unroll
    for (int c = 0; c < C_; ++c) { red[wv_][c] = a0[c]; red[wv_][C_ + c] = a1[c]; }
  __syncthreads();
  if (t < 2 * C_) {
    const float s = red[0][t] + red[1][t] + red[2][t] + red[3][t];
    if (t < C_) zlog[t * F_ + f] = s;
    else        olog[(t - C_) * F_ + f] = s;
  }
}

// ---------------- K6: gather per-row contributions + softmax ----------------
__global__ void nam_final(const float* __restrict__ x, const float* __restrict__ exu_b,
                          const float* __restrict__ emin,
                          const float* __restrict__ zlog, const float* __restrict__ olog,
                          const float* __restrict__ biasc, const float* __restrict__ logits_mid,
                          float* __restrict__ out)
{
  const int t = threadIdx.x;
  const int f = t & 127, sub = t >> 7;
  const int b = blockIdx.x * 2 + sub;
  const float d  = x[(size_t)b * F_ + f] - exu_b[f];
  const float em = emin[f];
  const bool is_zero = !(d > 0.f);
  const bool is_one  = (d > 0.f) && (d * em >= 1.f);
  float a[C_];
#pragma unroll
  for (int c = 0; c < C_; ++c) {
    const float zv = zlog[c * F_ + f];
    const float ov = olog[c * F_ + f];
    a[c] = is_zero ? zv : (is_one ? ov : 0.f);
  }
#pragma unroll
  for (int off = 32; off > 0; off >>= 1)
#pragma unroll
    for (int c = 0; c < C_; ++c) a[c] += __shfl_down(a[c], off);
  __shared__ float red[4][C_];
  __shared__ float lg[2][C_];
  const int wv_ = t >> 6, ln = t & 63;
  if (ln == 0)
#pragma unroll
    for (int c = 0; c < C_; ++c) red[wv_][c] = a[c];
  __syncthreads();
  if (t < 2 * C_) {
    const int rb = t / C_, c = t % C_;
    lg[rb][c] = red[rb * 2][c] + red[rb * 2 + 1][c]
              + logits_mid[(size_t)(blockIdx.x * 2 + rb) * C_ + c] + biasc[c];
  }
  __syncthreads();
  if (t < 2) {
    float mx = -3.0e38f;
#pragma unroll
    for (int c = 0; c < C_; ++c) mx = fmaxf(mx, lg[t][c]);
    float e[C_];
    float s = 0.f;
#pragma unroll
    for (int c = 0; c < C_; ++c) { e[c] = expf(lg[t][c] - mx); s += e[c]; }
    const float inv = 1.f / s;
#pragma unroll
    for (int c = 0; c < C_; ++c) out[(size_t)(blockIdx.x * 2 + t) * C_ + c] = e[c] * inv;
  }
}

extern "C" void kernel_launch(void* const* d_in, const int* in_sizes, int n_in,
                              void* d_out, int out_size, void* d_ws, size_t ws_size,
                              hipStream_t stream)
{
  const float* x     = (const float*)d_in[0];
  const float* exu_w = (const float*)d_in[1];
  const float* exu_b = (const float*)d_in[2];
  const float* W1    = (const float*)d_in[3];
  const float* b1    = (const float*)d_in[4];
  const float* W2    = (const float*)d_in[5];
  const float* b2    = (const float*)d_in[6];
  const float* b_out = (const float*)d_in[7];
  float* out = (float*)d_out;

  char* ws = (char*)d_ws;
  float* emin       = (float*)(ws + 0);                       //   512 B
  float* biasc      = (float*)(ws + 512);                     //    40 B (pad 576)
  int*   count      = (int*)  (ws + 576);                     //   512 B
  int*   listb      = (int*)  (ws + 1088);                    // 1 MB
  float* colsum1    = (float*)(ws + 1049664);                 // 256 KB
  float* zlog       = (float*)(ws + 1311808);                 // 5 KB
  float* olog       = (float*)(ws + 1316928);                 // 5 KB
  float* logits_mid = (float*)(ws + 1322048);                 // 80 KB
  unsigned long long* skeys_g = (unsigned long long*)(ws + 1404928);  // 1 MB
  int*   bout       = (int*)  (ws + 2453504);                 // 1 MB
  float* h2pre      = (float*)(ws + 4194304);                 // up to 512 MB (worst case)

  nam_sort<<<F_ + 1 + (B_ * C_ / 256), 256, 0, stream>>>(exu_w, b2, b_out, skeys_g,
                                                          emin, biasc, count, logits_mid);
  nam_classify<<<B_ / 2, 256, 0, stream>>>(x, exu_b, emin, count, listb);
  nam_stream<<<F_ * 2, 128, 0, stream>>>(x, exu_b, W1, skeys_g, listb, count,
                                          colsum1, h2pre, bout);
  nam_fin_mid<<<F_, 256, 0, stream>>>(count, bout, h2pre, colsum1, b1, W2, logits_mid);
  nam_tables<<<F_, 256, 0, stream>>>(colsum1, b1, W2, zlog, olog);
  nam_final<<<B_ / 2, 256, 0, stream>>>(x, exu_b, emin, zlog, olog, biasc, logits_mid, out);
}